// Round 1
// baseline (237.346 us; speedup 1.0000x reference)
//
#include <hip/hip_runtime.h>
#include <hip/hip_bf16.h>

#define N_NODES 100000
#define N_EDGES 1600000
#define D 128
#define N_TILES 6250             // N_NODES/16
#define NB 512                   // buckets
#define RPB 196                  // rows per bucket (512*196 = 100352 >= N_NODES)
#define BCAP 3584                // slab capacity: mean 3136 + 8 sigma (R9-validated margin)
#define SA_WGS 768               // scatterA workgroups (3/CU at 50KB LDS)
#define SA_EDGES 2084            // edges per scatterA WG (768*2084 = 1600512 >= 1.6M)
#define CAP 12                   // LDS staging depth per bucket (lambda~4.07, P(>12) ~ 3e-4)

typedef __bf16 bf16x8 __attribute__((ext_vector_type(8)));
typedef float  f32x4  __attribute__((ext_vector_type(4)));
typedef float  f32x2  __attribute__((ext_vector_type(2)));
typedef int    i32x2  __attribute__((ext_vector_type(2)));

// ---- K1: W transpose (fp32 -> bf16 WT) + zero bucket cursors ----
__global__ __launch_bounds__(256) void prep_kernel(const float* __restrict__ W,
                                                   __bf16* __restrict__ WT,
                                                   int* __restrict__ bucketCnt) {
    int t = blockIdx.x * 256 + threadIdx.x;   // 16384 threads
    int k = t >> 7, n = t & 127;
    WT[n * D + k] = (__bf16)W[t];
    if (t < NB) bucketCnt[t] = 0;
}

// ---- K2: GEMM h = bf16(x) @ bf16(W) (verified since R6) ----
__global__ __launch_bounds__(256) void gemm_kernel(
        const float* __restrict__ x,
        const __bf16* __restrict__ WT,
        __bf16* __restrict__ h) {
    __shared__ __bf16 lsm[4][16][144];
    const int wave = threadIdx.x >> 6;
    const int lane = threadIdx.x & 63;
    const int tile = blockIdx.x * 4 + wave;
    if (tile >= N_TILES) return;
    const int m = lane & 15, quad = lane >> 4;
    const float* xp = x + (size_t)(tile * 16 + m) * D + quad * 8;

    f32x4 acc[8];
#pragma unroll
    for (int ct = 0; ct < 8; ++ct) acc[ct] = (f32x4)(0.0f);
#pragma unroll
    for (int kk = 0; kk < 4; ++kk) {
        f32x4 a0 = *(const f32x4*)(xp + kk * 32);
        f32x4 a1 = *(const f32x4*)(xp + kk * 32 + 4);
        bf16x8 a;
#pragma unroll
        for (int j = 0; j < 4; ++j) { a[j] = (__bf16)a0[j]; a[j + 4] = (__bf16)a1[j]; }
#pragma unroll
        for (int ct = 0; ct < 8; ++ct) {
            bf16x8 b = *(const bf16x8*)(WT + (size_t)(ct * 16 + m) * D + kk * 32 + quad * 8);
            acc[ct] = __builtin_amdgcn_mfma_f32_16x16x32_bf16(a, b, acc[ct], 0, 0, 0);
        }
    }
#pragma unroll
    for (int ct = 0; ct < 8; ++ct)
#pragma unroll
        for (int r = 0; r < 4; ++r)
            lsm[wave][quad * 4 + r][ct * 16 + m] = (__bf16)acc[ct][r];
#pragma unroll
    for (int i = 0; i < 4; ++i) {
        int rl = i * 4 + quad;
        bf16x8 vv = *(const bf16x8*)&lsm[wave][rl][m * 8];
        *(bf16x8*)(h + (size_t)(tile * 16 + rl) * D + m * 8) = vv;
    }
}

// ---- K3: LDS-staged scatter into fixed-capacity bucket slabs ----
// pack = (localRow<<17) | col, val as bits; claims via global per-bucket cursor
// CAP=12 -> 50KB LDS -> 3 WGs/CU; grid 768 so all WGs co-resident (+50% waves)
__global__ __launch_bounds__(256) void scatterA_kernel(
        const int* __restrict__ rows, const int* __restrict__ cols,
        const float* __restrict__ vals,
        int* __restrict__ bucketCnt, i32x2* __restrict__ svcA) {
    __shared__ i32x2 buf[NB][CAP];   // 48 KB
    __shared__ int   cnt[NB];        // 2 KB
    for (int t = threadIdx.x; t < NB; t += 256) cnt[t] = 0;
    __syncthreads();
    const int base = blockIdx.x * SA_EDGES;
    for (int it = 0; it < 9; ++it) {             // ceil(2084/256)=9
        int idx = it * 256 + threadIdx.x;
        if (idx < SA_EDGES) {
            int e = base + idx;
            if (e < N_EDGES) {
                int r = rows[e];
                int b = r / RPB;                  // magic-mul division by 196
                int local = r - b * RPB;
                i32x2 pk;
                pk[0] = (local << 17) | cols[e];
                pk[1] = __float_as_int(vals[e]);
                int p = atomicAdd(&cnt[b], 1);
                if (p < CAP) buf[b][p] = pk;
                else {                             // rare overflow: direct claim
                    int g = atomicAdd(&bucketCnt[b], 1);
                    if (g < BCAP) svcA[(size_t)b * BCAP + g] = pk;
                }
            }
        }
    }
    __syncthreads();
    for (int t = threadIdx.x; t < NB; t += 256) {
        int n = min(cnt[t], CAP);
        if (n > 0) {
            int g = atomicAdd(&bucketCnt[t], n);
            i32x2* dst = svcA + (size_t)t * BCAP;
            for (int i = 0; i < n; ++i)
                if (g + i < BCAP) dst[g + i] = buf[t][i];   // contiguous run
        }
    }
}

// ---- K4: fused local sort (hist + single-wave shuffle scan) + segsum + relu ----
// one 1024-thread WG per bucket; register accumulators (R7 lesson: never
// accumulate the hot fp32 sums via LDS atomics).
__device__ __forceinline__ f32x2 bf2f(unsigned u) {
    f32x2 r;
    r[0] = __int_as_float(u << 16);
    r[1] = __int_as_float(u & 0xffff0000u);
    return r;
}

__global__ __launch_bounds__(1024, 8) void sortsum_kernel(
        const __bf16* __restrict__ h, const int* __restrict__ bucketCnt,
        const i32x2* __restrict__ svcA, float* __restrict__ out) {
    __shared__ i32x2 lbuf[BCAP];     // 28 KB
    __shared__ int   lhist[256];
    __shared__ int   send[256];      // inclusive scan (row ends)
    __shared__ int   lcur[256];      // scatter cursors (row starts, mutated)
    const int b   = blockIdx.x;
    const int tid = threadIdx.x;
    const int n   = min(bucketCnt[b], BCAP);
    const i32x2* win = svcA + (size_t)b * BCAP;

    if (tid < 256) lhist[tid] = 0;
    __syncthreads();

    // load window into registers (<=4 recs/thread) + LDS histogram
    i32x2 rec0, rec1, rec2, rec3;
    const int i0 = tid, i1 = tid + 1024, i2 = tid + 2048, i3 = tid + 3072;
    if (i0 < n) { rec0 = win[i0]; atomicAdd(&lhist[((unsigned)rec0[0]) >> 17], 1); }
    if (i1 < n) { rec1 = win[i1]; atomicAdd(&lhist[((unsigned)rec1[0]) >> 17], 1); }
    if (i2 < n) { rec2 = win[i2]; atomicAdd(&lhist[((unsigned)rec2[0]) >> 17], 1); }
    if (i3 < n) { rec3 = win[i3]; atomicAdd(&lhist[((unsigned)rec3[0]) >> 17], 1); }
    __syncthreads();

    // single-wave scan: wave 0, 4 consecutive bins per lane + shuffle scan
    if (tid < 64) {
        int b0 = lhist[tid * 4 + 0], b1 = lhist[tid * 4 + 1];
        int b2 = lhist[tid * 4 + 2], b3 = lhist[tid * 4 + 3];
        int p0 = b0, p1 = p0 + b1, p2 = p1 + b2, p3 = p2 + b3;
        int s = p3;
#pragma unroll
        for (int d = 1; d < 64; d <<= 1) {
            int t2 = __shfl_up(s, d, 64);
            if (tid >= d) s += t2;
        }
        int ex = s - p3;                 // exclusive prefix of this 4-bin group
        send[tid * 4 + 0] = ex + p0;
        send[tid * 4 + 1] = ex + p1;
        send[tid * 4 + 2] = ex + p2;
        send[tid * 4 + 3] = ex + p3;
        lcur[tid * 4 + 0] = ex;
        lcur[tid * 4 + 1] = ex + p0;
        lcur[tid * 4 + 2] = ex + p1;
        lcur[tid * 4 + 3] = ex + p2;
    }
    __syncthreads();

    // scatter registers into row-sorted LDS
    if (i0 < n) { int rl = ((unsigned)rec0[0]) >> 17; lbuf[atomicAdd(&lcur[rl], 1)] = rec0; }
    if (i1 < n) { int rl = ((unsigned)rec1[0]) >> 17; lbuf[atomicAdd(&lcur[rl], 1)] = rec1; }
    if (i2 < n) { int rl = ((unsigned)rec2[0]) >> 17; lbuf[atomicAdd(&lcur[rl], 1)] = rec2; }
    if (i3 < n) { int rl = ((unsigned)rec3[0]) >> 17; lbuf[atomicAdd(&lcur[rl], 1)] = rec3; }
    __syncthreads();

    // per-wave register-accumulator segsum, 8-deep gather pipeline
    const int wave = tid >> 6;
    const int lane = tid & 63;
    const char* hb = (const char*)h;
    const unsigned lo4 = (unsigned)lane * 4u;
    for (int rl = wave; rl < RPB; rl += 16) {
        int gr = b * RPB + rl;
        if (gr >= N_NODES) break;
        int s = rl ? send[rl - 1] : 0;
        int e = send[rl];

        f32x2 acc0 = (f32x2)(0.0f), acc1 = (f32x2)(0.0f);
        f32x2 acc2 = (f32x2)(0.0f), acc3 = (f32x2)(0.0f);
        int i = s;
        for (; i + 7 < e; i += 8) {
            i32x2 r0 = lbuf[i],     r1 = lbuf[i + 1], r2 = lbuf[i + 2], r3 = lbuf[i + 3];
            i32x2 r4 = lbuf[i + 4], r5 = lbuf[i + 5], r6 = lbuf[i + 6], r7 = lbuf[i + 7];
            unsigned o0 = (((unsigned)r0[0] & 0x1FFFFu) << 8) + lo4;
            unsigned o1 = (((unsigned)r1[0] & 0x1FFFFu) << 8) + lo4;
            unsigned o2 = (((unsigned)r2[0] & 0x1FFFFu) << 8) + lo4;
            unsigned o3 = (((unsigned)r3[0] & 0x1FFFFu) << 8) + lo4;
            unsigned o4 = (((unsigned)r4[0] & 0x1FFFFu) << 8) + lo4;
            unsigned o5 = (((unsigned)r5[0] & 0x1FFFFu) << 8) + lo4;
            unsigned o6 = (((unsigned)r6[0] & 0x1FFFFu) << 8) + lo4;
            unsigned o7 = (((unsigned)r7[0] & 0x1FFFFu) << 8) + lo4;
            unsigned u0 = *(const unsigned*)(hb + o0);
            unsigned u1 = *(const unsigned*)(hb + o1);
            unsigned u2 = *(const unsigned*)(hb + o2);
            unsigned u3 = *(const unsigned*)(hb + o3);
            unsigned u4 = *(const unsigned*)(hb + o4);
            unsigned u5 = *(const unsigned*)(hb + o5);
            unsigned u6 = *(const unsigned*)(hb + o6);
            unsigned u7 = *(const unsigned*)(hb + o7);
            acc0 += bf2f(u0) * __int_as_float(r0[1]);
            acc1 += bf2f(u1) * __int_as_float(r1[1]);
            acc2 += bf2f(u2) * __int_as_float(r2[1]);
            acc3 += bf2f(u3) * __int_as_float(r3[1]);
            acc0 += bf2f(u4) * __int_as_float(r4[1]);
            acc1 += bf2f(u5) * __int_as_float(r5[1]);
            acc2 += bf2f(u6) * __int_as_float(r6[1]);
            acc3 += bf2f(u7) * __int_as_float(r7[1]);
        }
        for (; i + 3 < e; i += 4) {
            i32x2 r0 = lbuf[i], r1 = lbuf[i + 1], r2 = lbuf[i + 2], r3 = lbuf[i + 3];
            unsigned o0 = (((unsigned)r0[0] & 0x1FFFFu) << 8) + lo4;
            unsigned o1 = (((unsigned)r1[0] & 0x1FFFFu) << 8) + lo4;
            unsigned o2 = (((unsigned)r2[0] & 0x1FFFFu) << 8) + lo4;
            unsigned o3 = (((unsigned)r3[0] & 0x1FFFFu) << 8) + lo4;
            unsigned u0 = *(const unsigned*)(hb + o0);
            unsigned u1 = *(const unsigned*)(hb + o1);
            unsigned u2 = *(const unsigned*)(hb + o2);
            unsigned u3 = *(const unsigned*)(hb + o3);
            acc0 += bf2f(u0) * __int_as_float(r0[1]);
            acc1 += bf2f(u1) * __int_as_float(r1[1]);
            acc2 += bf2f(u2) * __int_as_float(r2[1]);
            acc3 += bf2f(u3) * __int_as_float(r3[1]);
        }
        for (; i < e; ++i) {
            i32x2 r0 = lbuf[i];
            unsigned o0 = (((unsigned)r0[0] & 0x1FFFFu) << 8) + lo4;
            unsigned u0 = *(const unsigned*)(hb + o0);
            acc0 += bf2f(u0) * __int_as_float(r0[1]);
        }

        f32x2 t01 = acc0 + acc1, t23 = acc2 + acc3;
        f32x2 tt = t01 + t23;
        f32x2 o;
        o[0] = fmaxf(tt[0], 0.0f);
        o[1] = fmaxf(tt[1], 0.0f);
        __builtin_nontemporal_store(o, (f32x2*)(out + (size_t)gr * D + lane * 2));
    }
}

extern "C" void kernel_launch(void* const* d_in, const int* in_sizes, int n_in,
                              void* d_out, int out_size, void* d_ws, size_t ws_size,
                              hipStream_t stream) {
    const float* x    = (const float*)d_in[0];
    const float* w    = (const float*)d_in[1];
    const float* vals = (const float*)d_in[2];
    const int*   rows = (const int*)d_in[3];
    const int*   cols = (const int*)d_in[4];
    float*       out  = (float*)d_out;

    // ---- workspace (~40.3 MB) ----
    char* p = (char*)d_ws;
    __bf16* h         = (__bf16*)p;  p += (size_t)N_NODES * D * 2;          // 25.6 MB
    __bf16* WT        = (__bf16*)p;  p += (size_t)D * D * 2;                // 32 KB
    int*    bucketCnt = (int*)p;     p += 4096;                             // NB ints
    i32x2*  svcA      = (i32x2*)p;   p += (size_t)NB * BCAP * 8;            // 14.7 MB

    prep_kernel<<<64, 256, 0, stream>>>(w, WT, bucketCnt);
    gemm_kernel<<<(N_TILES + 3) / 4, 256, 0, stream>>>(x, WT, h);
    scatterA_kernel<<<SA_WGS, 256, 0, stream>>>(rows, cols, vals, bucketCnt, svcA);
    sortsum_kernel<<<NB, 1024, 0, stream>>>(h, bucketCnt, svcA, out);
}